// Round 1
// baseline (2496.738 us; speedup 1.0000x reference)
//
#include <hip/hip_runtime.h>

#define NC 100000
#define NA 1024
#define FA 4096

// ---------------- transpose: W [128][K] row-major -> WT [K][128] ----------------
__global__ void k_transpose(const float* __restrict__ W, float* __restrict__ WT, int K) {
    int idx = blockIdx.x * blockDim.x + threadIdx.x;
    if (idx < K * 128) {
        int k = idx >> 7, f = idx & 127;
        WT[idx] = W[f * K + k];
    }
}

// ---------------- art[i] = article_x . W_lin1[i] + b_lin1[i] ----------------
__global__ void k_art(const float* __restrict__ ax, const float* __restrict__ W,
                      const float* __restrict__ b, float* __restrict__ art) {
    int wave = (blockIdx.x * blockDim.x + threadIdx.x) >> 6;
    int lane = threadIdx.x & 63;
    if (wave >= NA) return;
    const float* wr = W + (size_t)wave * FA;
    float s = 0.f;
    #pragma unroll
    for (int i = 0; i < FA; i += 256) {
        float4 a  = *(const float4*)&ax[i + 4 * lane];
        float4 wv = *(const float4*)&wr[i + 4 * lane];
        s += a.x * wv.x + a.y * wv.y + a.z * wv.z + a.w * wv.w;
    }
    for (int off = 32; off; off >>= 1) s += __shfl_down(s, off);
    if (lane == 0) art[wave] = s + b[wave];
}

// ---------------- scalar scatter: agg[dst] += art[src]; cnt[dst] += 1 ----------------
__global__ void k_edge_scalar(const int* __restrict__ ei, int E,
                              const float* __restrict__ art,
                              float* __restrict__ agg, float* __restrict__ cnt) {
    int t = blockIdx.x * blockDim.x + threadIdx.x;
    int stride = gridDim.x * blockDim.x;
    for (int e = t; e < E; e += stride) {
        int s = ei[e], d = ei[E + e];
        atomicAdd(&agg[d], art[s]);
        atomicAdd(&cnt[d], 1.0f);
    }
}

// ---------------- vector scatter: agg[dst][:] += h[src][:]; cnt[dst] += 1 ----------------
__global__ void k_edge_vec(const int* __restrict__ ei, int E,
                           const float* __restrict__ h, float* __restrict__ agg,
                           float* __restrict__ cnt) {
    int t = blockIdx.x * blockDim.x + threadIdx.x;
    int total = E * 32;
    int stride = gridDim.x * blockDim.x;
    for (int i = t; i < total; i += stride) {
        int e = i >> 5, j = i & 31;
        int s = ei[e], d = ei[E + e];
        float4 m = *(const float4*)&h[(size_t)s * 128 + 4 * j];
        float* ap = &agg[(size_t)d * 128 + 4 * j];
        atomicAdd(ap + 0, m.x);
        atomicAdd(ap + 1, m.y);
        atomicAdd(ap + 2, m.z);
        atomicAdd(ap + 3, m.w);
        if (j == 0) atomicAdd(&cnt[d], 1.0f);
    }
}

// ---------------- generic rowwise GEMM: out[i][f] = act(X[i].WT[:,f] ...) ----------------
// WT is [K][128] (k-major). Each wave: 64 rows, lane owns f=lane and f=lane+64.
template<int K, bool RELU, bool ACCUM, bool SCAL, bool RSCALE, bool BIAS>
__global__ __launch_bounds__(256, 2)
void k_gemm(const float* __restrict__ X, const float* __restrict__ WT,
            const float* __restrict__ bias, const float* __restrict__ aggS,
            const float* __restrict__ cntS, const float* __restrict__ wlcol,
            const float* __restrict__ rcnt, float* __restrict__ out, int N) {
    __shared__ float xs[4][64 * 68];
    const int w = threadIdx.x >> 6, lane = threadIdx.x & 63;
    const int rowbase = (blockIdx.x * 4 + w) * 64;
    float acc0[64], acc1[64];
    #pragma unroll
    for (int r = 0; r < 64; ++r) { acc0[r] = 0.f; acc1[r] = 0.f; }
    const int cg = lane & 15, r0 = lane >> 4;
    float* xw = xs[w];

    for (int kt = 0; kt < K; kt += 64) {
        __syncthreads();
        // stage 64 rows x 64 k's, transposed to k-major [k][row] (stride 68)
        #pragma unroll
        for (int it = 0; it < 16; ++it) {
            int rl = 4 * it + r0;
            int row = rowbase + rl;
            float4 xv = make_float4(0.f, 0.f, 0.f, 0.f);
            if (row < N) xv = *(const float4*)&X[(size_t)row * K + kt + 4 * cg];
            xw[(4 * cg + 0) * 68 + rl] = xv.x;
            xw[(4 * cg + 1) * 68 + rl] = xv.y;
            xw[(4 * cg + 2) * 68 + rl] = xv.z;
            xw[(4 * cg + 3) * 68 + rl] = xv.w;
        }
        __syncthreads();
        #pragma unroll 1
        for (int k = 0; k < 64; ++k) {
            float w0 = WT[(size_t)(kt + k) * 128 + lane];
            float w1 = WT[(size_t)(kt + k) * 128 + lane + 64];
            const float4* xr = (const float4*)&xw[k * 68];
            #pragma unroll
            for (int q = 0; q < 16; ++q) {
                float4 xv = xr[q];
                acc0[4 * q + 0] = fmaf(w0, xv.x, acc0[4 * q + 0]);
                acc0[4 * q + 1] = fmaf(w0, xv.y, acc0[4 * q + 1]);
                acc0[4 * q + 2] = fmaf(w0, xv.z, acc0[4 * q + 2]);
                acc0[4 * q + 3] = fmaf(w0, xv.w, acc0[4 * q + 3]);
                acc1[4 * q + 0] = fmaf(w1, xv.x, acc1[4 * q + 0]);
                acc1[4 * q + 1] = fmaf(w1, xv.y, acc1[4 * q + 1]);
                acc1[4 * q + 2] = fmaf(w1, xv.z, acc1[4 * q + 2]);
                acc1[4 * q + 3] = fmaf(w1, xv.w, acc1[4 * q + 3]);
            }
        }
    }

    float b0 = BIAS ? bias[lane] : 0.f;
    float b1 = BIAS ? bias[lane + 64] : 0.f;
    float wl0 = SCAL ? wlcol[lane] : 0.f;
    float wl1 = SCAL ? wlcol[lane + 64] : 0.f;
    #pragma unroll
    for (int r = 0; r < 64; ++r) {
        int row = rowbase + r;
        if (row < N) {
            float v0 = acc0[r], v1 = acc1[r];
            if (RSCALE) {
                float c = rcnt[row]; c = c > 1.f ? c : 1.f;
                float inv = 1.f / c; v0 *= inv; v1 *= inv;
            }
            v0 += b0; v1 += b1;
            if (SCAL) {
                float c = cntS[row]; c = c > 1.f ? c : 1.f;
                float m = aggS[row] / c;
                v0 = fmaf(m, wl0, v0); v1 = fmaf(m, wl1, v1);
            }
            size_t o = (size_t)row * 128;
            if (ACCUM) { v0 += out[o + lane]; v1 += out[o + lane + 64]; }
            if (RELU) { v0 = fmaxf(v0, 0.f); v1 = fmaxf(v1, 0.f); }
            out[o + lane] = v0;
            out[o + lane + 64] = v1;
        }
    }
}

// ---------------- decoder: out[e] = Wd2 . relu(u[row] + v[col]) + bd2 ----------------
__global__ void k_decoder(const int* __restrict__ ei, int E,
                          const float* __restrict__ u, const float* __restrict__ v,
                          const float* __restrict__ wd2, const float* __restrict__ bd2,
                          float* __restrict__ out) {
    int gw = (blockIdx.x * blockDim.x + threadIdx.x) >> 6;
    int lane = threadIdx.x & 63;
    int nw = (gridDim.x * blockDim.x) >> 6;
    float wa = wd2[2 * lane], wb = wd2[2 * lane + 1];
    float bb = bd2[0];
    for (int e = gw; e < E; e += nw) {
        int r = ei[e], c = ei[E + e];
        float2 uu = *(const float2*)&u[(size_t)r * 128 + 2 * lane];
        float2 vv = *(const float2*)&v[(size_t)c * 128 + 2 * lane];
        float h0 = fmaxf(uu.x + vv.x, 0.f);
        float h1 = fmaxf(uu.y + vv.y, 0.f);
        float p = h0 * wa + h1 * wb;
        for (int off = 32; off; off >>= 1) p += __shfl_down(p, off);
        if (lane == 0) out[e] = p + bb;
    }
}

extern "C" void kernel_launch(void* const* d_in, const int* in_sizes, int n_in,
                              void* d_out, int out_size, void* d_ws, size_t ws_size,
                              hipStream_t stream) {
    const float* article_x = (const float*)d_in[0];
    const float* cx     = (const float*)d_in[1];
    const int*   e_wb   = (const int*)d_in[2];
    const int*   e_mb   = (const int*)d_in[3];
    const int*   e_cc   = (const int*)d_in[4];
    const float* W_lin1 = (const float*)d_in[5];
    const float* b_lin1 = (const float*)d_in[6];
    const float* Wl1    = (const float*)d_in[7];
    const float* bl1    = (const float*)d_in[8];
    const float* Wr1    = (const float*)d_in[9];
    const float* Wl2    = (const float*)d_in[10];
    const float* bl2    = (const float*)d_in[11];
    const float* Wr2    = (const float*)d_in[12];
    const float* Wl3    = (const float*)d_in[13];
    const float* bl3    = (const float*)d_in[14];
    const float* Wr3    = (const float*)d_in[15];
    const float* W_lin2 = (const float*)d_in[16];
    const float* b_lin2 = (const float*)d_in[17];
    const float* Wd1    = (const float*)d_in[18];
    const float* bd1    = (const float*)d_in[19];
    const float* Wd2    = (const float*)d_in[20];
    const float* bd2    = (const float*)d_in[21];
    float* out = (float*)d_out;

    const int E1 = in_sizes[2] / 2;
    const int E2 = in_sizes[3] / 2;
    const int E3 = in_sizes[4] / 2;

    float* ws = (float*)d_ws;
    size_t o = 0;
    float* art  = ws;      o += 1024;
    float* agg1 = ws + o;  o += NC;
    float* cnt1 = ws + o;  o += NC;
    float* agg2 = ws + o;  o += NC;
    float* cnt2 = ws + o;  o += NC;
    float* cnt3 = ws + o;  o += NC;
    float* tWr1   = ws + o; o += 256 * 128;
    float* tWr2   = ws + o; o += 128 * 128;
    float* tWl3   = ws + o; o += 128 * 128;
    float* tWr3   = ws + o; o += 256 * 128;
    float* tWlin2 = ws + o; o += 128 * 128;
    float* tWd1   = ws + o; o += 256 * 128;
    float* B1 = ws + o; o += (size_t)NC * 128;
    float* B2 = ws + o; o += (size_t)NC * 128;

    hipMemsetAsync(agg1, 0, 5 * NC * sizeof(float), stream);              // agg1,cnt1,agg2,cnt2,cnt3
    hipMemsetAsync(B2, 0, (size_t)NC * 128 * sizeof(float), stream);      // agg3

    k_transpose<<<128, 256, 0, stream>>>(Wr1, tWr1, 256);
    k_transpose<<<64, 256, 0, stream>>>(Wr2, tWr2, 128);
    k_transpose<<<64, 256, 0, stream>>>(Wl3, tWl3, 128);
    k_transpose<<<128, 256, 0, stream>>>(Wr3, tWr3, 256);
    k_transpose<<<64, 256, 0, stream>>>(W_lin2, tWlin2, 128);
    k_transpose<<<128, 256, 0, stream>>>(Wd1, tWd1, 256);

    k_art<<<256, 256, 0, stream>>>(article_x, W_lin1, b_lin1, art);

    k_edge_scalar<<<512, 256, 0, stream>>>(e_wb, E1, art, agg1, cnt1);
    k_edge_scalar<<<512, 256, 0, stream>>>(e_mb, E2, art, agg2, cnt2);

    const int GB = (NC + 255) / 256;  // 391 blocks, 4 waves x 64 rows each

    // h1 = relu(cx @ Wr1.T + bl1 + mean1*Wl1)          -> B1
    k_gemm<256, true, false, true, false, true><<<GB, 256, 0, stream>>>(
        cx, tWr1, bl1, agg1, cnt1, Wl1, nullptr, B1, NC);
    // h2 = relu(h1 @ Wr2.T + bl2 + mean2*Wl2)          -> B1 (in place)
    k_gemm<128, true, false, true, false, true><<<GB, 256, 0, stream>>>(
        B1, tWr2, bl2, agg2, cnt2, Wl2, nullptr, B1, NC);
    // agg3[dst] += h2[src], cnt3
    k_edge_vec<<<2048, 256, 0, stream>>>(e_cc, E3, B1, B2, cnt3);
    // h3a = (agg3 @ Wl3.T)/cnt3 + bl3                  -> B1 (h2 dead)
    k_gemm<128, false, false, false, true, true><<<GB, 256, 0, stream>>>(
        B2, tWl3, bl3, nullptr, nullptr, nullptr, cnt3, B1, NC);
    // h3 = relu(h3a + cx @ Wr3.T)                      -> B1 (accumulate in place)
    k_gemm<256, true, true, false, false, false><<<GB, 256, 0, stream>>>(
        cx, tWr3, nullptr, nullptr, nullptr, nullptr, nullptr, B1, NC);
    // z = h3 @ W_lin2.T + b_lin2                       -> B1 (in place)
    k_gemm<128, false, false, false, false, true><<<GB, 256, 0, stream>>>(
        B1, tWlin2, b_lin2, nullptr, nullptr, nullptr, nullptr, B1, NC);
    // v = z @ Wd1[:,128:].T                            -> B2 (agg3 dead)
    k_gemm<128, false, false, false, false, false><<<GB, 256, 0, stream>>>(
        B1, tWd1 + 128 * 128, nullptr, nullptr, nullptr, nullptr, nullptr, B2, NC);
    // u = z @ Wd1[:,:128].T + bd1                      -> B1 (in place, after v)
    k_gemm<128, false, false, false, false, true><<<GB, 256, 0, stream>>>(
        B1, tWd1, bd1, nullptr, nullptr, nullptr, nullptr, B1, NC);

    k_decoder<<<512, 256, 0, stream>>>(e_cc, E3, B1, B2, Wd2, bd2, out);
}

// Round 2
// 1314.604 us; speedup vs baseline: 1.8992x; 1.8992x over previous
//
#include <hip/hip_runtime.h>

#define NC 100000
#define NA 1024
#define FA 4096

// ---------------- transpose: W [128][K] row-major -> WT [K][128] ----------------
__global__ void k_transpose(const float* __restrict__ W, float* __restrict__ WT, int K) {
    int idx = blockIdx.x * blockDim.x + threadIdx.x;
    if (idx < K * 128) {
        int k = idx >> 7, f = idx & 127;
        WT[idx] = W[f * K + k];
    }
}

// ---------------- art[i] = article_x . W_lin1[i] + b_lin1[i] ----------------
__global__ void k_art(const float* __restrict__ ax, const float* __restrict__ W,
                      const float* __restrict__ b, float* __restrict__ art) {
    int wave = (blockIdx.x * blockDim.x + threadIdx.x) >> 6;
    int lane = threadIdx.x & 63;
    if (wave >= NA) return;
    const float* wr = W + (size_t)wave * FA;
    float s = 0.f;
    #pragma unroll
    for (int i = 0; i < FA; i += 256) {
        float4 a  = *(const float4*)&ax[i + 4 * lane];
        float4 wv = *(const float4*)&wr[i + 4 * lane];
        s += a.x * wv.x + a.y * wv.y + a.z * wv.z + a.w * wv.w;
    }
    for (int off = 32; off; off >>= 1) s += __shfl_down(s, off);
    if (lane == 0) art[wave] = s + b[wave];
}

// ---------------- scalar scatter: agg[dst] += art[src]; cnt[dst] += 1 ----------------
__global__ void k_edge_scalar(const int* __restrict__ ei, int E,
                              const float* __restrict__ art,
                              float* __restrict__ agg, float* __restrict__ cnt) {
    int t = blockIdx.x * blockDim.x + threadIdx.x;
    int stride = gridDim.x * blockDim.x;
    for (int e = t; e < E; e += stride) {
        int s = ei[e], d = ei[E + e];
        atomicAdd(&agg[d], art[s]);
        atomicAdd(&cnt[d], 1.0f);
    }
}

// ---------------- CSR build: histogram ----------------
__global__ void k_hist(const int* __restrict__ ei, int E, int* __restrict__ deg) {
    int t = blockIdx.x * blockDim.x + threadIdx.x;
    int stride = gridDim.x * blockDim.x;
    for (int e = t; e < E; e += stride) atomicAdd(&deg[ei[E + e]], 1);
}

// ---------------- CSR build: scan stage 1 (per-block 1024-elem exclusive scan) ----------------
__global__ void k_scan1(const int* __restrict__ deg, int* __restrict__ pre,
                        int* __restrict__ blksum) {
    __shared__ int ts[256];
    int base = blockIdx.x * 1024 + threadIdx.x * 4;
    int v0 = 0, v1 = 0, v2 = 0, v3 = 0;
    if (base + 0 < NC) v0 = deg[base + 0];
    if (base + 1 < NC) v1 = deg[base + 1];
    if (base + 2 < NC) v2 = deg[base + 2];
    if (base + 3 < NC) v3 = deg[base + 3];
    int tsum = v0 + v1 + v2 + v3;
    ts[threadIdx.x] = tsum;
    __syncthreads();
    for (int off = 1; off < 256; off <<= 1) {
        int y = (threadIdx.x >= off) ? ts[threadIdx.x - off] : 0;
        __syncthreads();
        ts[threadIdx.x] += y;
        __syncthreads();
    }
    int excl = ts[threadIdx.x] - tsum;
    if (base + 0 < NC) pre[base + 0] = excl;
    if (base + 1 < NC) pre[base + 1] = excl + v0;
    if (base + 2 < NC) pre[base + 2] = excl + v0 + v1;
    if (base + 3 < NC) pre[base + 3] = excl + v0 + v1 + v2;
    if (threadIdx.x == 255) blksum[blockIdx.x] = ts[255];
}

// ---------------- CSR build: scan stage 2 (single block over block sums) ----------------
__global__ void k_scan2(int* __restrict__ blksum, int NB) {
    __shared__ int ts[256];
    int v = (threadIdx.x < NB) ? blksum[threadIdx.x] : 0;
    ts[threadIdx.x] = v;
    __syncthreads();
    for (int off = 1; off < 256; off <<= 1) {
        int y = (threadIdx.x >= off) ? ts[threadIdx.x - off] : 0;
        __syncthreads();
        ts[threadIdx.x] += y;
        __syncthreads();
    }
    if (threadIdx.x < NB) blksum[threadIdx.x] = ts[threadIdx.x] - v;  // exclusive
}

// ---------------- CSR build: scan stage 3 (add back, emit off/cursor/cntf) ----------------
__global__ void k_scan3(const int* __restrict__ pre, const int* __restrict__ blksum,
                        const int* __restrict__ deg, int* __restrict__ off,
                        int* __restrict__ cursor, float* __restrict__ cntf) {
    int i = blockIdx.x * blockDim.x + threadIdx.x;
    if (i < NC) {
        int o = pre[i] + blksum[i >> 10];
        off[i] = o;
        cursor[i] = o;
        cntf[i] = (float)deg[i];
    }
}

// ---------------- CSR build: scatter src indices into dst-sorted buckets ----------------
__global__ void k_csr_scatter(const int* __restrict__ ei, int E,
                              int* __restrict__ cursor, int* __restrict__ srcs) {
    int t = blockIdx.x * blockDim.x + threadIdx.x;
    int stride = gridDim.x * blockDim.x;
    for (int e = t; e < E; e += stride) {
        int s = ei[e], d = ei[E + e];
        int p = atomicAdd(&cursor[d], 1);
        srcs[p] = s;
    }
}

// ---------------- CSR aggregate: agg[n][:] = sum_{j in bucket(n)} h[srcs[j]][:] ----------------
__global__ __launch_bounds__(256)
void k_csr_agg(const int* __restrict__ off, const int* __restrict__ deg,
               const int* __restrict__ srcs, const float* __restrict__ h,
               float* __restrict__ agg) {
    int node = (blockIdx.x * blockDim.x + threadIdx.x) >> 6;
    int lane = threadIdx.x & 63;
    if (node >= NC) return;
    int b = off[node], d = deg[node];
    float sx = 0.f, sy = 0.f;
    for (int j = 0; j < d; ++j) {
        int src = srcs[b + j];
        float2 m = *(const float2*)&h[(size_t)src * 128 + 2 * lane];
        sx += m.x; sy += m.y;
    }
    float2 r = make_float2(sx, sy);
    *(float2*)&agg[(size_t)node * 128 + 2 * lane] = r;
}

// ---------------- generic rowwise GEMM: out[i][f] = act(X[i].WT[:,f] ...) ----------------
// WT is [K][128] (k-major). Each wave: 64 rows, lane owns f=lane and f=lane+64.
template<int K, bool RELU, bool ACCUM, bool SCAL, bool RSCALE, bool BIAS>
__global__ __launch_bounds__(256, 2)
void k_gemm(const float* __restrict__ X, const float* __restrict__ WT,
            const float* __restrict__ bias, const float* __restrict__ aggS,
            const float* __restrict__ cntS, const float* __restrict__ wlcol,
            const float* __restrict__ rcnt, float* __restrict__ out, int N) {
    __shared__ float xs[4][64 * 68];
    const int w = threadIdx.x >> 6, lane = threadIdx.x & 63;
    const int rowbase = (blockIdx.x * 4 + w) * 64;
    float acc0[64], acc1[64];
    #pragma unroll
    for (int r = 0; r < 64; ++r) { acc0[r] = 0.f; acc1[r] = 0.f; }
    const int cg = lane & 15, r0 = lane >> 4;
    float* xw = xs[w];

    for (int kt = 0; kt < K; kt += 64) {
        __syncthreads();
        #pragma unroll
        for (int it = 0; it < 16; ++it) {
            int rl = 4 * it + r0;
            int row = rowbase + rl;
            float4 xv = make_float4(0.f, 0.f, 0.f, 0.f);
            if (row < N) xv = *(const float4*)&X[(size_t)row * K + kt + 4 * cg];
            xw[(4 * cg + 0) * 68 + rl] = xv.x;
            xw[(4 * cg + 1) * 68 + rl] = xv.y;
            xw[(4 * cg + 2) * 68 + rl] = xv.z;
            xw[(4 * cg + 3) * 68 + rl] = xv.w;
        }
        __syncthreads();
        #pragma unroll 1
        for (int k = 0; k < 64; ++k) {
            float w0 = WT[(size_t)(kt + k) * 128 + lane];
            float w1 = WT[(size_t)(kt + k) * 128 + lane + 64];
            const float4* xr = (const float4*)&xw[k * 68];
            #pragma unroll
            for (int q = 0; q < 16; ++q) {
                float4 xv = xr[q];
                acc0[4 * q + 0] = fmaf(w0, xv.x, acc0[4 * q + 0]);
                acc0[4 * q + 1] = fmaf(w0, xv.y, acc0[4 * q + 1]);
                acc0[4 * q + 2] = fmaf(w0, xv.z, acc0[4 * q + 2]);
                acc0[4 * q + 3] = fmaf(w0, xv.w, acc0[4 * q + 3]);
                acc1[4 * q + 0] = fmaf(w1, xv.x, acc1[4 * q + 0]);
                acc1[4 * q + 1] = fmaf(w1, xv.y, acc1[4 * q + 1]);
                acc1[4 * q + 2] = fmaf(w1, xv.z, acc1[4 * q + 2]);
                acc1[4 * q + 3] = fmaf(w1, xv.w, acc1[4 * q + 3]);
            }
        }
    }

    float b0 = BIAS ? bias[lane] : 0.f;
    float b1 = BIAS ? bias[lane + 64] : 0.f;
    float wl0 = SCAL ? wlcol[lane] : 0.f;
    float wl1 = SCAL ? wlcol[lane + 64] : 0.f;
    #pragma unroll
    for (int r = 0; r < 64; ++r) {
        int row = rowbase + r;
        if (row < N) {
            float v0 = acc0[r], v1 = acc1[r];
            if (RSCALE) {
                float c = rcnt[row]; c = c > 1.f ? c : 1.f;
                float inv = 1.f / c; v0 *= inv; v1 *= inv;
            }
            v0 += b0; v1 += b1;
            if (SCAL) {
                float c = cntS[row]; c = c > 1.f ? c : 1.f;
                float m = aggS[row] / c;
                v0 = fmaf(m, wl0, v0); v1 = fmaf(m, wl1, v1);
            }
            size_t o = (size_t)row * 128;
            if (ACCUM) { v0 += out[o + lane]; v1 += out[o + lane + 64]; }
            if (RELU) { v0 = fmaxf(v0, 0.f); v1 = fmaxf(v1, 0.f); }
            out[o + lane] = v0;
            out[o + lane + 64] = v1;
        }
    }
}

// ---------------- decoder: out[e] = Wd2 . relu(u[row] + v[col]) + bd2 ----------------
__global__ void k_decoder(const int* __restrict__ ei, int E,
                          const float* __restrict__ u, const float* __restrict__ v,
                          const float* __restrict__ wd2, const float* __restrict__ bd2,
                          float* __restrict__ out) {
    int gw = (blockIdx.x * blockDim.x + threadIdx.x) >> 6;
    int lane = threadIdx.x & 63;
    int nw = (gridDim.x * blockDim.x) >> 6;
    float wa = wd2[2 * lane], wb = wd2[2 * lane + 1];
    float bb = bd2[0];
    for (int e = gw; e < E; e += nw) {
        int r = ei[e], c = ei[E + e];
        float2 uu = *(const float2*)&u[(size_t)r * 128 + 2 * lane];
        float2 vv = *(const float2*)&v[(size_t)c * 128 + 2 * lane];
        float h0 = fmaxf(uu.x + vv.x, 0.f);
        float h1 = fmaxf(uu.y + vv.y, 0.f);
        float p = h0 * wa + h1 * wb;
        for (int off = 32; off; off >>= 1) p += __shfl_down(p, off);
        if (lane == 0) out[e] = p + bb;
    }
}

extern "C" void kernel_launch(void* const* d_in, const int* in_sizes, int n_in,
                              void* d_out, int out_size, void* d_ws, size_t ws_size,
                              hipStream_t stream) {
    const float* article_x = (const float*)d_in[0];
    const float* cx     = (const float*)d_in[1];
    const int*   e_wb   = (const int*)d_in[2];
    const int*   e_mb   = (const int*)d_in[3];
    const int*   e_cc   = (const int*)d_in[4];
    const float* W_lin1 = (const float*)d_in[5];
    const float* b_lin1 = (const float*)d_in[6];
    const float* Wl1    = (const float*)d_in[7];
    const float* bl1    = (const float*)d_in[8];
    const float* Wr1    = (const float*)d_in[9];
    const float* Wl2    = (const float*)d_in[10];
    const float* bl2    = (const float*)d_in[11];
    const float* Wr2    = (const float*)d_in[12];
    const float* Wl3    = (const float*)d_in[13];
    const float* bl3    = (const float*)d_in[14];
    const float* Wr3    = (const float*)d_in[15];
    const float* W_lin2 = (const float*)d_in[16];
    const float* b_lin2 = (const float*)d_in[17];
    const float* Wd1    = (const float*)d_in[18];
    const float* bd1    = (const float*)d_in[19];
    const float* Wd2    = (const float*)d_in[20];
    const float* bd2    = (const float*)d_in[21];
    float* out = (float*)d_out;

    const int E1 = in_sizes[2] / 2;
    const int E2 = in_sizes[3] / 2;
    const int E3 = in_sizes[4] / 2;

    float* ws = (float*)d_ws;
    size_t o = 0;
    float* art   = ws;      o += 1024;
    float* agg1  = ws + o;  o += NC;
    float* cnt1  = ws + o;  o += NC;
    float* agg2  = ws + o;  o += NC;
    float* cnt2  = ws + o;  o += NC;
    float* cnt3f = ws + o;  o += NC;
    float* tWr1   = ws + o; o += 256 * 128;
    float* tWr2   = ws + o; o += 128 * 128;
    float* tWl3   = ws + o; o += 128 * 128;
    float* tWr3   = ws + o; o += 256 * 128;
    float* tWlin2 = ws + o; o += 128 * 128;
    float* tWd1   = ws + o; o += 256 * 128;
    float* B1 = ws + o; o += (size_t)NC * 128;
    float* B2 = ws + o; o += (size_t)NC * 128;
    // int-typed CSR scratch
    int* deg    = (int*)(ws + o); o += NC;
    int* pre    = (int*)(ws + o); o += NC;
    int* off    = (int*)(ws + o); o += NC;
    int* cursor = (int*)(ws + o); o += NC;
    int* blksum = (int*)(ws + o); o += 256;
    int* srcs   = (int*)(ws + o); o += 800000;

    hipMemsetAsync(agg1, 0, 4 * NC * sizeof(float), stream);   // agg1,cnt1,agg2,cnt2
    hipMemsetAsync(deg, 0, NC * sizeof(int), stream);

    k_transpose<<<128, 256, 0, stream>>>(Wr1, tWr1, 256);
    k_transpose<<<64, 256, 0, stream>>>(Wr2, tWr2, 128);
    k_transpose<<<64, 256, 0, stream>>>(Wl3, tWl3, 128);
    k_transpose<<<128, 256, 0, stream>>>(Wr3, tWr3, 256);
    k_transpose<<<64, 256, 0, stream>>>(W_lin2, tWlin2, 128);
    k_transpose<<<128, 256, 0, stream>>>(Wd1, tWd1, 256);

    k_art<<<256, 256, 0, stream>>>(article_x, W_lin1, b_lin1, art);

    k_edge_scalar<<<512, 256, 0, stream>>>(e_wb, E1, art, agg1, cnt1);
    k_edge_scalar<<<512, 256, 0, stream>>>(e_mb, E2, art, agg2, cnt2);

    // CSR build for e_cc (dst-sorted buckets of src indices)
    const int NB = (NC + 1023) / 1024;  // 98
    k_hist<<<512, 256, 0, stream>>>(e_cc, E3, deg);
    k_scan1<<<NB, 256, 0, stream>>>(deg, pre, blksum);
    k_scan2<<<1, 256, 0, stream>>>(blksum, NB);
    k_scan3<<<(NC + 255) / 256, 256, 0, stream>>>(pre, blksum, deg, off, cursor, cnt3f);
    k_csr_scatter<<<512, 256, 0, stream>>>(e_cc, E3, cursor, srcs);

    const int GB = (NC + 255) / 256;  // 391 blocks, 4 waves x 64 rows each

    // h1 = relu(cx @ Wr1.T + bl1 + mean1*Wl1)          -> B1
    k_gemm<256, true, false, true, false, true><<<GB, 256, 0, stream>>>(
        cx, tWr1, bl1, agg1, cnt1, Wl1, nullptr, B1, NC);
    // h2 = relu(h1 @ Wr2.T + bl2 + mean2*Wl2)          -> B1 (in place)
    k_gemm<128, true, false, true, false, true><<<GB, 256, 0, stream>>>(
        B1, tWr2, bl2, agg2, cnt2, Wl2, nullptr, B1, NC);
    // agg3 = CSR gather-sum of h2                      -> B2
    k_csr_agg<<<(NC * 64 + 255) / 256, 256, 0, stream>>>(off, deg, srcs, B1, B2);
    // h3a = (agg3 @ Wl3.T)/cnt3 + bl3                  -> B1 (h2 dead)
    k_gemm<128, false, false, false, true, true><<<GB, 256, 0, stream>>>(
        B2, tWl3, bl3, nullptr, nullptr, nullptr, cnt3f, B1, NC);
    // h3 = relu(h3a + cx @ Wr3.T)                      -> B1 (accumulate in place)
    k_gemm<256, true, true, false, false, false><<<GB, 256, 0, stream>>>(
        cx, tWr3, nullptr, nullptr, nullptr, nullptr, nullptr, B1, NC);
    // z = h3 @ W_lin2.T + b_lin2                       -> B1 (in place)
    k_gemm<128, false, false, false, false, true><<<GB, 256, 0, stream>>>(
        B1, tWlin2, b_lin2, nullptr, nullptr, nullptr, nullptr, B1, NC);
    // v = z @ Wd1[:,128:].T                            -> B2 (agg3 dead)
    k_gemm<128, false, false, false, false, false><<<GB, 256, 0, stream>>>(
        B1, tWd1 + 128 * 128, nullptr, nullptr, nullptr, nullptr, nullptr, B2, NC);
    // u = z @ Wd1[:,:128].T + bd1                      -> B1 (in place, after v)
    k_gemm<128, false, false, false, false, true><<<GB, 256, 0, stream>>>(
        B1, tWd1, bd1, nullptr, nullptr, nullptr, nullptr, B1, NC);

    k_decoder<<<512, 256, 0, stream>>>(e_cc, E3, B1, B2, Wd2, bd2, out);
}

// Round 3
// 1062.853 us; speedup vs baseline: 2.3491x; 1.2369x over previous
//
#include <hip/hip_runtime.h>

#define NC 100000
#define NA 1024
#define FA 4096

// ---------------- transpose: W [128][K] row-major -> WT [K][128] ----------------
__global__ void k_transpose(const float* __restrict__ W, float* __restrict__ WT, int K) {
    int idx = blockIdx.x * blockDim.x + threadIdx.x;
    if (idx < K * 128) {
        int k = idx >> 7, f = idx & 127;
        WT[idx] = W[f * K + k];
    }
}

// ---------------- art[i] = article_x . W_lin1[i] + b_lin1[i] ----------------
__global__ void k_art(const float* __restrict__ ax, const float* __restrict__ W,
                      const float* __restrict__ b, float* __restrict__ art) {
    int wave = (blockIdx.x * blockDim.x + threadIdx.x) >> 6;
    int lane = threadIdx.x & 63;
    if (wave >= NA) return;
    const float* wr = W + (size_t)wave * FA;
    float s = 0.f;
    #pragma unroll
    for (int i = 0; i < FA; i += 256) {
        float4 a  = *(const float4*)&ax[i + 4 * lane];
        float4 wv = *(const float4*)&wr[i + 4 * lane];
        s += a.x * wv.x + a.y * wv.y + a.z * wv.z + a.w * wv.w;
    }
    for (int off = 32; off; off >>= 1) s += __shfl_down(s, off);
    if (lane == 0) art[wave] = s + b[wave];
}

// ---------------- scalar scatter: agg[dst] += art[src]; cnt[dst] += 1 ----------------
__global__ void k_edge_scalar(const int* __restrict__ ei, int E,
                              const float* __restrict__ art,
                              float* __restrict__ agg, float* __restrict__ cnt) {
    int t = blockIdx.x * blockDim.x + threadIdx.x;
    int stride = gridDim.x * blockDim.x;
    for (int e = t; e < E; e += stride) {
        int s = ei[e], d = ei[E + e];
        atomicAdd(&agg[d], art[s]);
        atomicAdd(&cnt[d], 1.0f);
    }
}

// ---------------- CSR build: histogram ----------------
__global__ void k_hist(const int* __restrict__ ei, int E, int* __restrict__ deg) {
    int t = blockIdx.x * blockDim.x + threadIdx.x;
    int stride = gridDim.x * blockDim.x;
    for (int e = t; e < E; e += stride) atomicAdd(&deg[ei[E + e]], 1);
}

// ---------------- CSR build: scan stage 1 (per-block 1024-elem exclusive scan) ----------------
__global__ void k_scan1(const int* __restrict__ deg, int* __restrict__ pre,
                        int* __restrict__ blksum) {
    __shared__ int ts[256];
    int base = blockIdx.x * 1024 + threadIdx.x * 4;
    int v0 = 0, v1 = 0, v2 = 0, v3 = 0;
    if (base + 0 < NC) v0 = deg[base + 0];
    if (base + 1 < NC) v1 = deg[base + 1];
    if (base + 2 < NC) v2 = deg[base + 2];
    if (base + 3 < NC) v3 = deg[base + 3];
    int tsum = v0 + v1 + v2 + v3;
    ts[threadIdx.x] = tsum;
    __syncthreads();
    for (int off = 1; off < 256; off <<= 1) {
        int y = (threadIdx.x >= off) ? ts[threadIdx.x - off] : 0;
        __syncthreads();
        ts[threadIdx.x] += y;
        __syncthreads();
    }
    int excl = ts[threadIdx.x] - tsum;
    if (base + 0 < NC) pre[base + 0] = excl;
    if (base + 1 < NC) pre[base + 1] = excl + v0;
    if (base + 2 < NC) pre[base + 2] = excl + v0 + v1;
    if (base + 3 < NC) pre[base + 3] = excl + v0 + v1 + v2;
    if (threadIdx.x == 255) blksum[blockIdx.x] = ts[255];
}

// ---------------- CSR build: scan stage 2 (single block over block sums) ----------------
__global__ void k_scan2(int* __restrict__ blksum, int NB) {
    __shared__ int ts[256];
    int v = (threadIdx.x < NB) ? blksum[threadIdx.x] : 0;
    ts[threadIdx.x] = v;
    __syncthreads();
    for (int off = 1; off < 256; off <<= 1) {
        int y = (threadIdx.x >= off) ? ts[threadIdx.x - off] : 0;
        __syncthreads();
        ts[threadIdx.x] += y;
        __syncthreads();
    }
    if (threadIdx.x < NB) blksum[threadIdx.x] = ts[threadIdx.x] - v;  // exclusive
}

// ---------------- CSR build: scan stage 3 (add back, emit off/cursor/cntf) ----------------
__global__ void k_scan3(const int* __restrict__ pre, const int* __restrict__ blksum,
                        const int* __restrict__ deg, int* __restrict__ off,
                        int* __restrict__ cursor, float* __restrict__ cntf) {
    int i = blockIdx.x * blockDim.x + threadIdx.x;
    if (i < NC) {
        int o = pre[i] + blksum[i >> 10];
        off[i] = o;
        cursor[i] = o;
        cntf[i] = (float)deg[i];
    }
}

// ---------------- CSR build: scatter (src, edge-id) into dst-sorted buckets ----------------
__global__ void k_csr_scatter(const int* __restrict__ ei, int E,
                              int* __restrict__ cursor, int* __restrict__ srcs,
                              int* __restrict__ eidx) {
    int t = blockIdx.x * blockDim.x + threadIdx.x;
    int stride = gridDim.x * blockDim.x;
    for (int e = t; e < E; e += stride) {
        int s = ei[e], d = ei[E + e];
        int p = atomicAdd(&cursor[d], 1);
        srcs[p] = s;
        eidx[p] = e;
    }
}

// ---------------- CSR aggregate: agg[n][:] = sum_{j in bucket(n)} h[srcs[j]][:] ----------------
__global__ __launch_bounds__(256)
void k_csr_agg(const int* __restrict__ off, const int* __restrict__ deg,
               const int* __restrict__ srcs, const float* __restrict__ h,
               float* __restrict__ agg) {
    int node = (blockIdx.x * blockDim.x + threadIdx.x) >> 6;
    int lane = threadIdx.x & 63;
    if (node >= NC) return;
    int b = off[node], d = deg[node];
    float sx = 0.f, sy = 0.f;
    for (int j = 0; j < d; ++j) {
        int src = srcs[b + j];
        float2 m = *(const float2*)&h[(size_t)src * 128 + 2 * lane];
        sx += m.x; sy += m.y;
    }
    float2 r = make_float2(sx, sy);
    *(float2*)&agg[(size_t)node * 128 + 2 * lane] = r;
}

// ---------------- generic rowwise GEMM: out[i][f] = act(X[i].WT[:,f] ...) ----------------
// WT is [K][128] (k-major). Each wave: 64 rows, lane owns f=lane and f=lane+64.
template<int K, bool RELU, bool ACCUM, bool SCAL, bool RSCALE, bool BIAS>
__global__ __launch_bounds__(256, 2)
void k_gemm(const float* __restrict__ X, const float* __restrict__ WT,
            const float* __restrict__ bias, const float* __restrict__ aggS,
            const float* __restrict__ cntS, const float* __restrict__ wlcol,
            const float* __restrict__ rcnt, float* __restrict__ out, int N) {
    __shared__ float xs[4][64 * 68];
    const int w = threadIdx.x >> 6, lane = threadIdx.x & 63;
    const int rowbase = (blockIdx.x * 4 + w) * 64;
    float acc0[64], acc1[64];
    #pragma unroll
    for (int r = 0; r < 64; ++r) { acc0[r] = 0.f; acc1[r] = 0.f; }
    const int cg = lane & 15, r0 = lane >> 4;
    float* xw = xs[w];

    for (int kt = 0; kt < K; kt += 64) {
        __syncthreads();
        #pragma unroll
        for (int it = 0; it < 16; ++it) {
            int rl = 4 * it + r0;
            int row = rowbase + rl;
            float4 xv = make_float4(0.f, 0.f, 0.f, 0.f);
            if (row < N) xv = *(const float4*)&X[(size_t)row * K + kt + 4 * cg];
            xw[(4 * cg + 0) * 68 + rl] = xv.x;
            xw[(4 * cg + 1) * 68 + rl] = xv.y;
            xw[(4 * cg + 2) * 68 + rl] = xv.z;
            xw[(4 * cg + 3) * 68 + rl] = xv.w;
        }
        __syncthreads();
        #pragma unroll 1
        for (int k = 0; k < 64; ++k) {
            float w0 = WT[(size_t)(kt + k) * 128 + lane];
            float w1 = WT[(size_t)(kt + k) * 128 + lane + 64];
            const float4* xr = (const float4*)&xw[k * 68];
            #pragma unroll
            for (int q = 0; q < 16; ++q) {
                float4 xv = xr[q];
                acc0[4 * q + 0] = fmaf(w0, xv.x, acc0[4 * q + 0]);
                acc0[4 * q + 1] = fmaf(w0, xv.y, acc0[4 * q + 1]);
                acc0[4 * q + 2] = fmaf(w0, xv.z, acc0[4 * q + 2]);
                acc0[4 * q + 3] = fmaf(w0, xv.w, acc0[4 * q + 3]);
                acc1[4 * q + 0] = fmaf(w1, xv.x, acc1[4 * q + 0]);
                acc1[4 * q + 1] = fmaf(w1, xv.y, acc1[4 * q + 1]);
                acc1[4 * q + 2] = fmaf(w1, xv.z, acc1[4 * q + 2]);
                acc1[4 * q + 3] = fmaf(w1, xv.w, acc1[4 * q + 3]);
            }
        }
    }

    float b0 = BIAS ? bias[lane] : 0.f;
    float b1 = BIAS ? bias[lane + 64] : 0.f;
    float wl0 = SCAL ? wlcol[lane] : 0.f;
    float wl1 = SCAL ? wlcol[lane + 64] : 0.f;
    #pragma unroll
    for (int r = 0; r < 64; ++r) {
        int row = rowbase + r;
        if (row < N) {
            float v0 = acc0[r], v1 = acc1[r];
            if (RSCALE) {
                float c = rcnt[row]; c = c > 1.f ? c : 1.f;
                float inv = 1.f / c; v0 *= inv; v1 *= inv;
            }
            v0 += b0; v1 += b1;
            if (SCAL) {
                float c = cntS[row]; c = c > 1.f ? c : 1.f;
                float m = aggS[row] / c;
                v0 = fmaf(m, wl0, v0); v1 = fmaf(m, wl1, v1);
            }
            size_t o = (size_t)row * 128;
            if (ACCUM) { v0 += out[o + lane]; v1 += out[o + lane + 64]; }
            if (RELU) { v0 = fmaxf(v0, 0.f); v1 = fmaxf(v1, 0.f); }
            out[o + lane] = v0;
            out[o + lane + 64] = v1;
        }
    }
}

// ---------------- decoder over CSR: per dst node, v-row in regs, gather u[src] ----------------
// wave = 1 dst node; 8 groups x 8 sublanes; group g handles bucket edge jb+g;
// sublane s owns features [16s, 16s+16).
__global__ __launch_bounds__(256)
void k_decoder_csr(const int* __restrict__ off, const int* __restrict__ deg,
                   const int* __restrict__ srcs, const int* __restrict__ eidx,
                   const float* __restrict__ u, const float* __restrict__ v,
                   const float* __restrict__ wd2, const float* __restrict__ bd2,
                   float* __restrict__ out) {
    int node = (blockIdx.x * blockDim.x + threadIdx.x) >> 6;
    if (node >= NC) return;
    int lane = threadIdx.x & 63;
    int g = lane >> 3, s = lane & 7;

    const float4* wp = (const float4*)&wd2[s * 16];
    float4 w0 = wp[0], w1 = wp[1], w2 = wp[2], w3 = wp[3];
    float bb = bd2[0];

    const float4* vp = (const float4*)&v[(size_t)node * 128 + s * 16];
    float4 v0 = vp[0], v1 = vp[1], v2 = vp[2], v3 = vp[3];

    int b = off[node], d = deg[node];
    for (int jb = 0; jb < d; jb += 8) {
        int j = jb + g;
        float p = 0.f;
        int eid = 0;
        if (j < d) {
            int src = srcs[b + j];
            eid = eidx[b + j];
            const float4* up = (const float4*)&u[(size_t)src * 128 + s * 16];
            float4 u0 = up[0], u1 = up[1], u2 = up[2], u3 = up[3];
            p  = w0.x * fmaxf(u0.x + v0.x, 0.f) + w0.y * fmaxf(u0.y + v0.y, 0.f)
               + w0.z * fmaxf(u0.z + v0.z, 0.f) + w0.w * fmaxf(u0.w + v0.w, 0.f);
            p += w1.x * fmaxf(u1.x + v1.x, 0.f) + w1.y * fmaxf(u1.y + v1.y, 0.f)
               + w1.z * fmaxf(u1.z + v1.z, 0.f) + w1.w * fmaxf(u1.w + v1.w, 0.f);
            p += w2.x * fmaxf(u2.x + v2.x, 0.f) + w2.y * fmaxf(u2.y + v2.y, 0.f)
               + w2.z * fmaxf(u2.z + v2.z, 0.f) + w2.w * fmaxf(u2.w + v2.w, 0.f);
            p += w3.x * fmaxf(u3.x + v3.x, 0.f) + w3.y * fmaxf(u3.y + v3.y, 0.f)
               + w3.z * fmaxf(u3.z + v3.z, 0.f) + w3.w * fmaxf(u3.w + v3.w, 0.f);
        }
        p += __shfl_xor(p, 1);
        p += __shfl_xor(p, 2);
        p += __shfl_xor(p, 4);
        if (j < d && s == 0) out[eid] = p + bb;
    }
}

extern "C" void kernel_launch(void* const* d_in, const int* in_sizes, int n_in,
                              void* d_out, int out_size, void* d_ws, size_t ws_size,
                              hipStream_t stream) {
    const float* article_x = (const float*)d_in[0];
    const float* cx     = (const float*)d_in[1];
    const int*   e_wb   = (const int*)d_in[2];
    const int*   e_mb   = (const int*)d_in[3];
    const int*   e_cc   = (const int*)d_in[4];
    const float* W_lin1 = (const float*)d_in[5];
    const float* b_lin1 = (const float*)d_in[6];
    const float* Wl1    = (const float*)d_in[7];
    const float* bl1    = (const float*)d_in[8];
    const float* Wr1    = (const float*)d_in[9];
    const float* Wl2    = (const float*)d_in[10];
    const float* bl2    = (const float*)d_in[11];
    const float* Wr2    = (const float*)d_in[12];
    const float* Wl3    = (const float*)d_in[13];
    const float* bl3    = (const float*)d_in[14];
    const float* Wr3    = (const float*)d_in[15];
    const float* W_lin2 = (const float*)d_in[16];
    const float* b_lin2 = (const float*)d_in[17];
    const float* Wd1    = (const float*)d_in[18];
    const float* bd1    = (const float*)d_in[19];
    const float* Wd2    = (const float*)d_in[20];
    const float* bd2    = (const float*)d_in[21];
    float* out = (float*)d_out;

    const int E1 = in_sizes[2] / 2;
    const int E2 = in_sizes[3] / 2;
    const int E3 = in_sizes[4] / 2;

    float* ws = (float*)d_ws;
    size_t o = 0;
    float* art   = ws;      o += 1024;
    float* agg1  = ws + o;  o += NC;
    float* cnt1  = ws + o;  o += NC;
    float* agg2  = ws + o;  o += NC;
    float* cnt2  = ws + o;  o += NC;
    float* cnt3f = ws + o;  o += NC;
    float* tWr1   = ws + o; o += 256 * 128;
    float* tWr2   = ws + o; o += 128 * 128;
    float* tWl3   = ws + o; o += 128 * 128;
    float* tWr3   = ws + o; o += 256 * 128;
    float* tWlin2 = ws + o; o += 128 * 128;
    float* tWd1   = ws + o; o += 256 * 128;
    float* B1 = ws + o; o += (size_t)NC * 128;
    float* B2 = ws + o; o += (size_t)NC * 128;
    // int-typed CSR scratch
    int* deg    = (int*)(ws + o); o += NC;
    int* pre    = (int*)(ws + o); o += NC;
    int* off    = (int*)(ws + o); o += NC;
    int* cursor = (int*)(ws + o); o += NC;
    int* blksum = (int*)(ws + o); o += 256;
    int* srcs   = (int*)(ws + o); o += 800000;
    int* eidx   = (int*)(ws + o); o += 800000;

    hipMemsetAsync(agg1, 0, 4 * NC * sizeof(float), stream);   // agg1,cnt1,agg2,cnt2
    hipMemsetAsync(deg, 0, NC * sizeof(int), stream);

    k_transpose<<<128, 256, 0, stream>>>(Wr1, tWr1, 256);
    k_transpose<<<64, 256, 0, stream>>>(Wr2, tWr2, 128);
    k_transpose<<<64, 256, 0, stream>>>(Wl3, tWl3, 128);
    k_transpose<<<128, 256, 0, stream>>>(Wr3, tWr3, 256);
    k_transpose<<<64, 256, 0, stream>>>(W_lin2, tWlin2, 128);
    k_transpose<<<128, 256, 0, stream>>>(Wd1, tWd1, 256);

    k_art<<<256, 256, 0, stream>>>(article_x, W_lin1, b_lin1, art);

    k_edge_scalar<<<512, 256, 0, stream>>>(e_wb, E1, art, agg1, cnt1);
    k_edge_scalar<<<512, 256, 0, stream>>>(e_mb, E2, art, agg2, cnt2);

    // CSR build for e_cc (dst-sorted buckets of (src, edge-id))
    const int NB = (NC + 1023) / 1024;  // 98
    k_hist<<<512, 256, 0, stream>>>(e_cc, E3, deg);
    k_scan1<<<NB, 256, 0, stream>>>(deg, pre, blksum);
    k_scan2<<<1, 256, 0, stream>>>(blksum, NB);
    k_scan3<<<(NC + 255) / 256, 256, 0, stream>>>(pre, blksum, deg, off, cursor, cnt3f);
    k_csr_scatter<<<512, 256, 0, stream>>>(e_cc, E3, cursor, srcs, eidx);

    const int GB = (NC + 255) / 256;   // 391 blocks, 4 waves x 64 rows each
    const int GW = (NC * 64 + 255) / 256;  // 1 wave per node

    // h1 = relu(cx @ Wr1.T + bl1 + mean1*Wl1)          -> B1
    k_gemm<256, true, false, true, false, true><<<GB, 256, 0, stream>>>(
        cx, tWr1, bl1, agg1, cnt1, Wl1, nullptr, B1, NC);
    // h2 = relu(h1 @ Wr2.T + bl2 + mean2*Wl2)          -> B1 (in place)
    k_gemm<128, true, false, true, false, true><<<GB, 256, 0, stream>>>(
        B1, tWr2, bl2, agg2, cnt2, Wl2, nullptr, B1, NC);
    // agg3 = CSR gather-sum of h2                      -> B2
    k_csr_agg<<<GW, 256, 0, stream>>>(off, deg, srcs, B1, B2);
    // h3a = (agg3 @ Wl3.T)/cnt3 + bl3                  -> B1 (h2 dead)
    k_gemm<128, false, false, false, true, true><<<GB, 256, 0, stream>>>(
        B2, tWl3, bl3, nullptr, nullptr, nullptr, cnt3f, B1, NC);
    // h3 = relu(h3a + cx @ Wr3.T)                      -> B1 (accumulate in place)
    k_gemm<256, true, true, false, false, false><<<GB, 256, 0, stream>>>(
        cx, tWr3, nullptr, nullptr, nullptr, nullptr, nullptr, B1, NC);
    // z = h3 @ W_lin2.T + b_lin2                       -> B1 (in place)
    k_gemm<128, false, false, false, false, true><<<GB, 256, 0, stream>>>(
        B1, tWlin2, b_lin2, nullptr, nullptr, nullptr, nullptr, B1, NC);
    // v = z @ Wd1[:,128:].T                            -> B2 (agg3 dead)
    k_gemm<128, false, false, false, false, false><<<GB, 256, 0, stream>>>(
        B1, tWd1 + 128 * 128, nullptr, nullptr, nullptr, nullptr, nullptr, B2, NC);
    // u = z @ Wd1[:,:128].T + bd1                      -> B1 (in place, after v)
    k_gemm<128, false, false, false, false, true><<<GB, 256, 0, stream>>>(
        B1, tWd1, bd1, nullptr, nullptr, nullptr, nullptr, B1, NC);

    // decoder: out[eid] = Wd2 . relu(u[src] + v[dst]) + bd2, iterated per dst bucket
    k_decoder_csr<<<GW, 256, 0, stream>>>(off, deg, srcs, eidx, B1, B2, Wd2, bd2, out);
}